// Round 1
// baseline (4056.815 us; speedup 1.0000x reference)
//
#include <hip/hip_runtime.h>

typedef _Float16 h16;
typedef h16 h16x8 __attribute__((ext_vector_type(8)));
typedef float f32x4 __attribute__((ext_vector_type(4)));

#define MFMA16(a, b, c) __builtin_amdgcn_mfma_f32_16x16x32_f16(a, b, c, 0, 0, 0)

typedef __attribute__((address_space(1))) const char gconst_char;
typedef __attribute__((address_space(3))) char lds_char;
#define GL_LDS16(g, l) __builtin_amdgcn_global_load_lds((gconst_char*)(g), (lds_char*)(l), 16, 0, 0)

// ---------------- workspace layout (bytes) ----------------
#define WIN_OFF   0
#define WIN_CSH   17408                      // [32n][264k] halfs = 16896B, 17 x 1KB staging calls
#define WUP_OFF   (WIN_OFF + 8 * WIN_CSH)    // 139264
#define WUP_CSH   17408
#define WDN_OFF   (WUP_OFF + 32 * WUP_CSH)   // 696320
#define WDN_CSH   20480                      // [256n][40k] halfs, 20 calls
#define WCOMB_OFF (WDN_OFF + 32 * WDN_CSH)   // 1351680
#define WCOMB_CSH 33792                      // [32n][520k] halfs = 33280B, 33 calls
#define WYT_OFF   (WCOMB_OFF + 8 * WCOMB_CSH) // 1622016
#define WYT_CSH   20480
#define WHEAD_OFF (WYT_OFF + 8 * WYT_CSH)    // 1785856
#define WHEAD_SZ  9216                       // [16n][264k] halfs = 8448B, 9 calls
#define ZY_OFF    (WHEAD_OFF + WHEAD_SZ)     // 1795072
#define ZY_BYTES  (131072UL * 512UL * 2UL)   // [B][512] halfs: z cols 0..255, y cols 256..511

// ---------------- mega kernel LDS layout ----------------
#define L_WUP0 0
#define L_WUP1 17408
#define L_WDN0 34816
#define L_WDN1 55296
#define L_HS   75776        // + wave*2560 : [32][40] halfs per wave
#define L_BUP  96256        // f32[1024]
#define L_BDN  100352       // f32[256]
#define L_LNW  101376
#define L_LNB  102400
#define SMEM_MEGA 103424
// Zt transpose buffer: aliases weight buffers, per-wave slice of 8448B ([16][264] halfs)

// ---------------- comb kernel LDS layout ----------------
#define C_WC0 0
#define C_WC1 33792
#define C_WY0 67584
#define C_WY1 88064
#define C_GS  108544        // + wave*2560
#define C_BC  129024
#define C_BY  130048
#define SMEM_COMB 131072

#define SMEM_HEAD 9216

__device__ __forceinline__ void stage_calls(const char* src, char* dst, int calls, int wave,
                                            int nw, int lane) {
  for (int i = wave; i < calls; i += nw)
    GL_LDS16(src + i * 1024 + lane * 16, dst + i * 1024);
}

__device__ __forceinline__ float gelu_f(float x) {
  // 0.5x(1+tanh(sqrt(2/pi)(x+0.044715x^3))) == x*sigmoid(1.59576912x + 0.07135484x^3)
  float t = x * (1.5957691216f + 0.0713548354f * x * x);
  float e = __expf(-t);
  return x * __builtin_amdgcn_rcpf(1.0f + e);
}

// ================= prep kernels: fp32 -> fp16, pre-blocked staging layouts =================
// Family A: n-chunked blocks [CHN][KPp], element = W[k][n] (B-operand, n-major, k-contig)
__global__ void prepA_kernel(const float* __restrict__ src, h16* __restrict__ dst,
                             int K, int KPp, int CHN, int Nsrc, int CSHh, int tot) {
  for (int d = blockIdx.x * 256 + threadIdx.x; d < tot; d += gridDim.x * 256) {
    int chunk = d / CSHh, r = d % CSHh;
    float v = 0.0f;
    if (r < CHN * KPp) {
      int nl = r / KPp, k = r % KPp;
      int n = chunk * CHN + nl;
      if (k < K && n < Nsrc) v = src[(long)k * Nsrc + n];
    }
    dst[d] = (h16)v;
  }
}
// Family B: k-chunked blocks [N][KP2p], element = W[chunk*Kc+kp][n]
__global__ void prepB_kernel(const float* __restrict__ src, h16* __restrict__ dst,
                             int Kc, int KP2p, int N, int CSHh, int tot) {
  for (int d = blockIdx.x * 256 + threadIdx.x; d < tot; d += gridDim.x * 256) {
    int chunk = d / CSHh, r = d % CSHh;
    float v = 0.0f;
    if (r < N * KP2p) {
      int n = r / KP2p, kp = r % KP2p;
      if (kp < Kc) v = src[(long)(chunk * Kc + kp) * N + n];
    }
    dst[d] = (h16)v;
  }
}

// ================= mega kernel: (optional in-proj) + 6 fused FFN+LN iterations =================
// wg = 512 thr (8 waves), 256 rows/wg, wave owns 32 rows (2 row-tiles of 16)
__global__ __launch_bounds__(512) void mega_kernel(
    const float* x, h16* zy,
    const char* __restrict__ winP, const char* __restrict__ wupP, const char* __restrict__ wdnP,
    const float* __restrict__ b_in, const float* __restrict__ b_up,
    const float* __restrict__ b_down, const float* __restrict__ ln_w,
    const float* __restrict__ ln_b, int first) {
  extern __shared__ char smem[];
  const int tid = threadIdx.x, wave = tid >> 6, lane = tid & 63;
  const int q = lane >> 4, c = lane & 15;
  const long m0 = (long)blockIdx.x * 256 + wave * 32;

  float* bupL = (float*)(smem + L_BUP);
  float* bdnL = (float*)(smem + L_BDN);
  float* lnwL = (float*)(smem + L_LNW);
  float* lnbL = (float*)(smem + L_LNB);
  for (int i = tid; i < 1024; i += 512) bupL[i] = b_up[i];
  if (tid < 256) { bdnL[tid] = b_down[tid]; lnwL[tid] = ln_w[tid]; lnbL[tid] = ln_b[tid]; }

  f32x4 acc2[2][16];   // z / accumulator, D-layout: row = rt*16 + q*4 + r, col = nt*16 + c
  h16x8 az[2][8];      // A-fragments of z (or x): A[m=c][k=kk*32+q*8+j]
  h16* hsH = (h16*)(smem + L_HS + wave * 2560);
  const f32x4 vzero = {0.0f, 0.0f, 0.0f, 0.0f};

  if (first) {
    // ---- in-proj: z = x @ W_in + b_in ----
#pragma unroll
    for (int rt = 0; rt < 2; ++rt)
#pragma unroll
      for (int kk = 0; kk < 8; ++kk) {
        const float* p = x + (m0 + rt * 16 + c) * 256 + kk * 32 + q * 8;
        f32x4 u0 = *(const f32x4*)p;
        f32x4 u1 = *(const f32x4*)(p + 4);
        h16x8 a;
        a[0] = (h16)u0[0]; a[1] = (h16)u0[1]; a[2] = (h16)u0[2]; a[3] = (h16)u0[3];
        a[4] = (h16)u1[0]; a[5] = (h16)u1[1]; a[6] = (h16)u1[2]; a[7] = (h16)u1[3];
        az[rt][kk] = a;
      }
#pragma unroll
    for (int rt = 0; rt < 2; ++rt)
#pragma unroll
      for (int nt = 0; nt < 16; ++nt) acc2[rt][nt] = vzero;

    stage_calls(winP, smem + L_WUP0, 17, wave, 8, lane);
    __syncthreads();
#pragma unroll
    for (int ncI = 0; ncI < 8; ++ncI) {
      if (ncI < 7)
        stage_calls(winP + (ncI + 1) * WIN_CSH, smem + (((ncI + 1) & 1) ? L_WUP1 : L_WUP0),
                    17, wave, 8, lane);
      const char* wb = smem + ((ncI & 1) ? L_WUP1 : L_WUP0);
#pragma unroll
      for (int kk = 0; kk < 8; ++kk)
#pragma unroll
        for (int nt = 0; nt < 2; ++nt) {
          h16x8 b = *(const h16x8*)(wb + ((nt * 16 + c) * 264 + kk * 32 + q * 8) * 2);
#pragma unroll
          for (int rt = 0; rt < 2; ++rt)
            acc2[rt][ncI * 2 + nt] = MFMA16(az[rt][kk], b, acc2[rt][ncI * 2 + nt]);
        }
      __syncthreads();
    }
#pragma unroll
    for (int nt = 0; nt < 16; ++nt) {
      float bi = b_in[nt * 16 + c];
#pragma unroll
      for (int rt = 0; rt < 2; ++rt)
#pragma unroll
        for (int r = 0; r < 4; ++r) acc2[rt][nt][r] += bi;
    }
  } else {
    // ---- resume z from zy (fp16) ----
#pragma unroll
    for (int rt = 0; rt < 2; ++rt)
#pragma unroll
      for (int kk = 0; kk < 8; ++kk)
        az[rt][kk] = *(const h16x8*)(zy + (m0 + rt * 16 + c) * 512 + kk * 32 + q * 8);
#pragma unroll
    for (int rt = 0; rt < 2; ++rt)
#pragma unroll
      for (int nt = 0; nt < 16; ++nt)
#pragma unroll
        for (int r = 0; r < 4; ++r)
          acc2[rt][nt][r] = (float)zy[(m0 + rt * 16 + q * 4 + r) * 512 + nt * 16 + c];
  }

  for (int it = 0; it < 6; ++it) {
    if (it > 0 || first) {
      // ---- Zt: D-layout z (acc2) -> fp16 A-fragments via per-wave LDS slice ----
      h16* zth = (h16*)(smem + wave * 8448);
#pragma unroll
      for (int rt = 0; rt < 2; ++rt) {
#pragma unroll
        for (int nt = 0; nt < 16; ++nt)
#pragma unroll
          for (int r = 0; r < 4; ++r)
            zth[(q * 4 + r) * 264 + nt * 16 + c] = (h16)acc2[rt][nt][r];
#pragma unroll
        for (int kk = 0; kk < 8; ++kk)
          az[rt][kk] = *(const h16x8*)(zth + c * 264 + kk * 32 + q * 8);
      }
    }
    __syncthreads();  // all waves done with Zt slices (they alias weight buffers)
    stage_calls(wupP, smem + L_WUP0, 17, wave, 8, lane);
    stage_calls(wdnP, smem + L_WDN0, 20, wave, 8, lane);
    __syncthreads();  // chunk 0 staged

    for (int nc = 0; nc < 32; ++nc) {
      if (nc < 31) {
        int nb = (nc + 1) & 1;
        stage_calls(wupP + (nc + 1) * WUP_CSH, smem + (nb ? L_WUP1 : L_WUP0), 17, wave, 8, lane);
        stage_calls(wdnP + (nc + 1) * WDN_CSH, smem + (nb ? L_WDN1 : L_WDN0), 20, wave, 8, lane);
      }
      const char* wub = smem + ((nc & 1) ? L_WUP1 : L_WUP0);
      const char* wdb = smem + ((nc & 1) ? L_WDN1 : L_WDN0);

      // GEMM1: h_pre = z @ W_up[:, nc*32 : nc*32+32]
      f32x4 acc1[2][2];
      acc1[0][0] = vzero; acc1[0][1] = vzero; acc1[1][0] = vzero; acc1[1][1] = vzero;
#pragma unroll
      for (int kk = 0; kk < 8; ++kk)
#pragma unroll
        for (int nt = 0; nt < 2; ++nt) {
          h16x8 b = *(const h16x8*)(wub + ((nt * 16 + c) * 264 + kk * 32 + q * 8) * 2);
#pragma unroll
          for (int rt = 0; rt < 2; ++rt) acc1[rt][nt] = MFMA16(az[rt][kk], b, acc1[rt][nt]);
        }
      // gelu + bias -> Hs (per-wave)
#pragma unroll
      for (int rt = 0; rt < 2; ++rt)
#pragma unroll
        for (int nt = 0; nt < 2; ++nt) {
          float bu = bupL[nc * 32 + nt * 16 + c];
#pragma unroll
          for (int r = 0; r < 4; ++r) {
            float g = gelu_f(acc1[rt][nt][r] + bu);
            hsH[(rt * 16 + q * 4 + r) * 40 + nt * 16 + c] = (h16)g;
          }
        }
      h16x8 ah[2];
#pragma unroll
      for (int rt = 0; rt < 2; ++rt)
        ah[rt] = *(const h16x8*)(hsH + (rt * 16 + c) * 40 + q * 8);
      // GEMM2: acc2 += h @ W_down[nc*32 : nc*32+32, :]
#pragma unroll
      for (int nt = 0; nt < 16; ++nt) {
        h16x8 b = *(const h16x8*)(wdb + ((nt * 16 + c) * 40 + q * 8) * 2);
#pragma unroll
        for (int rt = 0; rt < 2; ++rt) acc2[rt][nt] = MFMA16(ah[rt], b, acc2[rt][nt]);
      }
      __syncthreads();
    }

    // ---- epilogue: + b_down, LayerNorm (in registers, quad-wide butterfly) ----
#pragma unroll
    for (int rt = 0; rt < 2; ++rt) {
      float sum[4] = {0, 0, 0, 0}, sq[4] = {0, 0, 0, 0};
#pragma unroll
      for (int nt = 0; nt < 16; ++nt) {
        float bd = bdnL[nt * 16 + c];
#pragma unroll
        for (int r = 0; r < 4; ++r) {
          float v = acc2[rt][nt][r] + bd;
          acc2[rt][nt][r] = v;
          sum[r] += v;
          sq[r] += v * v;
        }
      }
#pragma unroll
      for (int r = 0; r < 4; ++r)
#pragma unroll
        for (int m = 1; m < 16; m <<= 1) {
          sum[r] += __shfl_xor(sum[r], m, 16);
          sq[r] += __shfl_xor(sq[r], m, 16);
        }
      float mu[4], rs[4];
#pragma unroll
      for (int r = 0; r < 4; ++r) {
        mu[r] = sum[r] * (1.0f / 256.0f);
        float var = sq[r] * (1.0f / 256.0f) - mu[r] * mu[r];
        rs[r] = __builtin_amdgcn_rsqf(var + 1e-5f);
      }
#pragma unroll
      for (int nt = 0; nt < 16; ++nt) {
        float w = lnwL[nt * 16 + c], bb = lnbL[nt * 16 + c];
#pragma unroll
        for (int r = 0; r < 4; ++r)
          acc2[rt][nt][r] = (acc2[rt][nt][r] - mu[r]) * rs[r] * w + bb;
      }
    }
  }

  // ---- hand off z (fp16) ----
#pragma unroll
  for (int rt = 0; rt < 2; ++rt)
#pragma unroll
    for (int nt = 0; nt < 16; ++nt)
#pragma unroll
      for (int r = 0; r < 4; ++r)
        zy[(m0 + rt * 16 + q * 4 + r) * 512 + nt * 16 + c] = (h16)acc2[rt][nt][r];
}

// ================= comb kernel: g = gelu([z|y]@W_comb + b_comb); y += g@W_yt + b_yt =================
__global__ __launch_bounds__(512) void comb_kernel(
    h16* zy, const char* __restrict__ wcP, const char* __restrict__ wytP,
    const float* __restrict__ b_comb, const float* __restrict__ b_yt,
    const float* __restrict__ y_init, int first) {
  extern __shared__ char smem[];
  const int tid = threadIdx.x, wave = tid >> 6, lane = tid & 63;
  const int q = lane >> 4, c = lane & 15;
  const long m0 = (long)blockIdx.x * 256 + wave * 32;

  float* bcL = (float*)(smem + C_BC);
  float* byL = (float*)(smem + C_BY);
  if (tid < 256) { bcL[tid] = b_comb[tid]; byL[tid] = b_yt[tid]; }

  f32x4 acc2[2][16];  // y accumulator
  if (first) {
#pragma unroll
    for (int nt = 0; nt < 16; ++nt) {
      float yv = y_init[nt * 16 + c];
#pragma unroll
      for (int rt = 0; rt < 2; ++rt)
#pragma unroll
        for (int r = 0; r < 4; ++r) acc2[rt][nt][r] = yv;
    }
  } else {
#pragma unroll
    for (int rt = 0; rt < 2; ++rt)
#pragma unroll
      for (int nt = 0; nt < 16; ++nt)
#pragma unroll
        for (int r = 0; r < 4; ++r)
          acc2[rt][nt][r] = (float)zy[(m0 + rt * 16 + q * 4 + r) * 512 + 256 + nt * 16 + c];
  }
  h16* gsH = (h16*)(smem + C_GS + wave * 2560);
  const f32x4 vzero = {0.0f, 0.0f, 0.0f, 0.0f};

  stage_calls(wcP, smem + C_WC0, 33, wave, 8, lane);
  stage_calls(wytP, smem + C_WY0, 20, wave, 8, lane);
  __syncthreads();

  for (int nc = 0; nc < 8; ++nc) {
    if (nc < 7) {
      int nb = (nc + 1) & 1;
      stage_calls(wcP + (nc + 1) * WCOMB_CSH, smem + (nb ? C_WC1 : C_WC0), 33, wave, 8, lane);
      stage_calls(wytP + (nc + 1) * WYT_CSH, smem + (nb ? C_WY1 : C_WY0), 20, wave, 8, lane);
    }
    const char* wcb = smem + ((nc & 1) ? C_WC1 : C_WC0);
    const char* wyb = smem + ((nc & 1) ? C_WY1 : C_WY0);

    // GEMM-g: [z|y] @ W_comb[:, nc*32 : +32]  (zy row IS the concatenated 512-vector)
    f32x4 acc1[2][2];
    acc1[0][0] = vzero; acc1[0][1] = vzero; acc1[1][0] = vzero; acc1[1][1] = vzero;
#pragma unroll
    for (int kk = 0; kk < 16; ++kk) {
      h16x8 a[2];
#pragma unroll
      for (int rt = 0; rt < 2; ++rt)
        a[rt] = *(const h16x8*)(zy + (m0 + rt * 16 + c) * 512 + kk * 32 + q * 8);
#pragma unroll
      for (int nt = 0; nt < 2; ++nt) {
        h16x8 b = *(const h16x8*)(wcb + ((nt * 16 + c) * 520 + kk * 32 + q * 8) * 2);
#pragma unroll
        for (int rt = 0; rt < 2; ++rt) acc1[rt][nt] = MFMA16(a[rt], b, acc1[rt][nt]);
      }
    }
#pragma unroll
    for (int rt = 0; rt < 2; ++rt)
#pragma unroll
      for (int nt = 0; nt < 2; ++nt) {
        float bc = bcL[nc * 32 + nt * 16 + c];
#pragma unroll
        for (int r = 0; r < 4; ++r) {
          float g = gelu_f(acc1[rt][nt][r] + bc);
          gsH[(rt * 16 + q * 4 + r) * 40 + nt * 16 + c] = (h16)g;
        }
      }
    h16x8 ah[2];
#pragma unroll
    for (int rt = 0; rt < 2; ++rt)
      ah[rt] = *(const h16x8*)(gsH + (rt * 16 + c) * 40 + q * 8);
#pragma unroll
    for (int nt = 0; nt < 16; ++nt) {
      h16x8 b = *(const h16x8*)(wyb + ((nt * 16 + c) * 40 + q * 8) * 2);
#pragma unroll
      for (int rt = 0; rt < 2; ++rt) acc2[rt][nt] = MFMA16(ah[rt], b, acc2[rt][nt]);
    }
    __syncthreads();
  }

#pragma unroll
  for (int nt = 0; nt < 16; ++nt) {
    float by = byL[nt * 16 + c];
#pragma unroll
    for (int rt = 0; rt < 2; ++rt)
#pragma unroll
      for (int r = 0; r < 4; ++r)
        zy[(m0 + rt * 16 + q * 4 + r) * 512 + 256 + nt * 16 + c] = (h16)(acc2[rt][nt][r] + by);
  }
}

// ================= head kernel: out = y @ W_head + b_head =================
__global__ __launch_bounds__(256) void head_kernel(const h16* zy, const char* __restrict__ whP,
                                                   const float* __restrict__ b_head,
                                                   float* __restrict__ out) {
  extern __shared__ char smem[];
  const int tid = threadIdx.x, wave = tid >> 6, lane = tid & 63;
  const int q = lane >> 4, c = lane & 15;
  const long m0 = (long)blockIdx.x * 128 + wave * 32;

  stage_calls(whP, smem, 9, wave, 4, lane);
  __syncthreads();

  f32x4 acc[2];
  const f32x4 vzero = {0.0f, 0.0f, 0.0f, 0.0f};
  acc[0] = vzero; acc[1] = vzero;
#pragma unroll
  for (int kk = 0; kk < 8; ++kk) {
    h16x8 b = *(const h16x8*)(smem + (c * 264 + kk * 32 + q * 8) * 2);
#pragma unroll
    for (int rt = 0; rt < 2; ++rt) {
      h16x8 a = *(const h16x8*)(zy + (m0 + rt * 16 + c) * 512 + 256 + kk * 32 + q * 8);
      acc[rt] = MFMA16(a, b, acc[rt]);
    }
  }
  if (c < 10) {
    float bh = b_head[c];
#pragma unroll
    for (int rt = 0; rt < 2; ++rt)
#pragma unroll
      for (int r = 0; r < 4; ++r)
        out[(m0 + rt * 16 + q * 4 + r) * 10 + c] = acc[rt][r] + bh;
  }
}

// ================= host =================
extern "C" void kernel_launch(void* const* d_in, const int* in_sizes, int n_in, void* d_out,
                              int out_size, void* d_ws, size_t ws_size, hipStream_t stream) {
  (void)in_sizes; (void)n_in; (void)out_size;
  const float* x      = (const float*)d_in[0];
  const float* W_in   = (const float*)d_in[1];
  const float* b_in   = (const float*)d_in[2];
  const float* y_init = (const float*)d_in[3];
  const float* W_up   = (const float*)d_in[4];
  const float* b_up   = (const float*)d_in[5];
  const float* W_down = (const float*)d_in[6];
  const float* b_down = (const float*)d_in[7];
  const float* ln_w   = (const float*)d_in[8];
  const float* ln_b   = (const float*)d_in[9];
  const float* W_comb = (const float*)d_in[10];
  const float* b_comb = (const float*)d_in[11];
  const float* W_yt   = (const float*)d_in[12];
  const float* b_yt   = (const float*)d_in[13];
  const float* W_head = (const float*)d_in[14];
  const float* b_head = (const float*)d_in[15];

  char* ws = (char*)d_ws;
  h16* winP   = (h16*)(ws + WIN_OFF);
  h16* wupP   = (h16*)(ws + WUP_OFF);
  h16* wdnP   = (h16*)(ws + WDN_OFF);
  h16* wcombP = (h16*)(ws + WCOMB_OFF);
  h16* wytP   = (h16*)(ws + WYT_OFF);
  h16* wheadP = (h16*)(ws + WHEAD_OFF);
  // z|y state buffer: in ws if it fits, else alias the x input buffer (row-local, safe)
  h16* zy = (ws_size >= (size_t)ZY_OFF + ZY_BYTES) ? (h16*)(ws + ZY_OFF) : (h16*)d_in[0];

  hipFuncSetAttribute((const void*)mega_kernel, hipFuncAttributeMaxDynamicSharedMemorySize,
                      SMEM_MEGA);
  hipFuncSetAttribute((const void*)comb_kernel, hipFuncAttributeMaxDynamicSharedMemorySize,
                      SMEM_COMB);

  // prep: cast+transpose+block all weights into fp16 staging layouts
  {
    int tot;
    tot = 8 * (WIN_CSH / 2);
    prepA_kernel<<<dim3((tot + 255) / 256), dim3(256), 0, stream>>>(W_in, winP, 256, 264, 32, 256, WIN_CSH / 2, tot);
    tot = 32 * (WUP_CSH / 2);
    prepA_kernel<<<dim3((tot + 255) / 256), dim3(256), 0, stream>>>(W_up, wupP, 256, 264, 32, 1024, WUP_CSH / 2, tot);
    tot = 8 * (WCOMB_CSH / 2);
    prepA_kernel<<<dim3((tot + 255) / 256), dim3(256), 0, stream>>>(W_comb, wcombP, 512, 520, 32, 256, WCOMB_CSH / 2, tot);
    tot = WHEAD_SZ / 2;
    prepA_kernel<<<dim3((tot + 255) / 256), dim3(256), 0, stream>>>(W_head, wheadP, 256, 264, 16, 10, WHEAD_SZ / 2, tot);
    tot = 32 * (WDN_CSH / 2);
    prepB_kernel<<<dim3((tot + 255) / 256), dim3(256), 0, stream>>>(W_down, wdnP, 32, 40, 256, WDN_CSH / 2, tot);
    tot = 8 * (WYT_CSH / 2);
    prepB_kernel<<<dim3((tot + 255) / 256), dim3(256), 0, stream>>>(W_yt, wytP, 32, 40, 256, WYT_CSH / 2, tot);
  }

  for (int h = 0; h < 3; ++h) {
    mega_kernel<<<dim3(512), dim3(512), SMEM_MEGA, stream>>>(
        x, zy, (const char*)winP, (const char*)wupP, (const char*)wdnP, b_in, b_up, b_down,
        ln_w, ln_b, (h == 0) ? 1 : 0);
    comb_kernel<<<dim3(512), dim3(512), SMEM_COMB, stream>>>(
        zy, (const char*)wcombP, (const char*)wytP, b_comb, b_yt, y_init, (h == 0) ? 1 : 0);
  }
  head_kernel<<<dim3(1024), dim3(256), SMEM_HEAD, stream>>>(zy, (const char*)wheadP, b_head,
                                                            (float*)d_out);
}